// Round 7
// baseline (535.569 us; speedup 1.0000x reference)
//
#include <hip/hip_runtime.h>
#include <math.h>

// Problem constants
#define BATCH 128
#define NPER 400
#define EPG 6400
#define NEDGE 819200
#define F_IN 400
#define HD 128
#define K1 320
#define K2 256
#define K3 205

typedef __bf16 bf16x8 __attribute__((ext_vector_type(8)));
typedef float f32x4 __attribute__((ext_vector_type(4)));

__device__ __forceinline__ unsigned short f2bf(float f) {
    unsigned u = __builtin_bit_cast(unsigned, f);
    unsigned r = u + 0x7fffu + ((u >> 16) & 1u);
    return (unsigned short)(r >> 16);
}
__device__ __forceinline__ float bf2f(unsigned short s) {
    unsigned u = ((unsigned)s) << 16;
    return __builtin_bit_cast(float, u);
}

// ---------------- workspace layout ----------------
static constexpr size_t SZ_TREL = 51200ull * 128 * 4;
static constexpr size_t OFF_TREL = 0;
static constexpr size_t OFF_H    = OFF_TREL + SZ_TREL;
static constexpr size_t OFF_HP   = OFF_H + SZ_TREL;
static constexpr size_t OFF_SC   = OFF_HP + 40960ull * 128 * 4;
static constexpr size_t OFF_IDX  = OFF_SC + 51200ull * 4;
static constexpr size_t OFF_VALS = OFF_IDX + 40960ull * 4;
static constexpr size_t OFF_NEWID= OFF_VALS + 40960ull * 4;
static constexpr size_t OFF_ES   = OFF_NEWID + 51200ull * 4;
static constexpr size_t OFF_ED   = OFF_ES + (size_t)NEDGE * 4;
static constexpr size_t OFF_EM   = OFF_ED + (size_t)NEDGE * 4;
static constexpr size_t OFF_Z    = OFF_EM + (size_t)NEDGE * 4;
static constexpr size_t OFF_COFF = OFF_Z + 128ull * 256 * 4;
static constexpr size_t OFF_CDEG = OFF_COFF + 51200ull * 4;
static constexpr size_t OFF_CSRC = OFF_CDEG + 51200ull * 4;
static constexpr size_t OFF_W1H  = OFF_CSRC + (size_t)NEDGE * 4;
static constexpr size_t OFF_W1L  = OFF_W1H + 256ull * 416 * 2;
static constexpr size_t OFF_W2H  = OFF_W1L + 256ull * 416 * 2;
static constexpr size_t OFF_W2L  = OFF_W2H + 256ull * 128 * 2;
static constexpr size_t OFF_W3H  = OFF_W2L + 256ull * 128 * 2;
static constexpr size_t OFF_W3L  = OFF_W3H + 256ull * 128 * 2;

// ---------------- weight split prep ----------------
__global__ __launch_bounds__(256) void prep_w(const float* __restrict__ Wrel,
                                              const float* __restrict__ Wroot,
                                              unsigned short* __restrict__ wh,
                                              unsigned short* __restrict__ wl,
                                              int Kd, int Kpad) {
    int k = blockIdx.x * 256 + threadIdx.x;
    int n = blockIdx.y;
    if (k >= Kpad) return;
    float v = 0.f;
    if (k < Kd) v = (n < 128) ? Wrel[n * Kd + k] : Wroot[(n - 128) * Kd + k];
    unsigned short hi = f2bf(v);
    unsigned short lo = f2bf(v - bf2f(hi));
    wh[(size_t)n * Kpad + k] = hi;
    wl[(size_t)n * Kpad + k] = lo;
}

// ---------------- MFMA GEMM (bf16x3 split): [t_rel | h] = A @ W^T ----------
// A fp32 [M][Kd], split to bf16 hi/lo in-register, staged in LDS (20 KB).
// B (weights, pre-split bf16) read as fragments DIRECTLY from global (L2-hot,
// 426 KB/layer) -- no B staging: halves LDS traffic, kills write conflicts.
__global__ __launch_bounds__(256) void gemm_mfma(
    const float* __restrict__ A, const unsigned short* __restrict__ wh,
    const unsigned short* __restrict__ wl,
    float* __restrict__ t_rel, float* __restrict__ h,
    int Kd, int Kpad, int Ksteps) {
    __shared__ unsigned short S[10240];      // A: 2 planes x 128 rows x 40 shorts
    unsigned short* Al = S;
    const int tid = threadIdx.x;
    const int m0 = blockIdx.x * 128;
    const int n0 = blockIdx.y * 128;
    const int wid = tid >> 6;
    const int lane = tid & 63;
    const int lm = lane & 15;
    const int qd = lane >> 4;
    const int wm0 = (wid >> 1) * 64;
    const int wn0 = (wid & 1) * 64;
    const int sr = tid >> 1;
    const int shf = tid & 1;

    f32x4 acc[4][4];
#pragma unroll
    for (int i = 0; i < 4; i++)
#pragma unroll
        for (int j = 0; j < 4; j++) acc[i][j] = (f32x4){0.f, 0.f, 0.f, 0.f};

    const float* Ab = A + (size_t)(m0 + sr) * Kd + shf * 16;
    // B fragment base: row n0+wn0+j*16+lm, k offset qd*8
    const unsigned short* Bh0 = wh + (size_t)(n0 + wn0 + lm) * Kpad + qd * 8;
    const unsigned short* Bo0 = wl + (size_t)(n0 + wn0 + lm) * Kpad + qd * 8;
    unsigned short* Aw = &Al[sr * 40 + shf * 16];

    for (int s = 0; s < Ksteps; s++) {
        const int k0 = s * 32;
        // ---- B hi fragments from global (L2) ----
        bf16x8 bhf[4];
#pragma unroll
        for (int j = 0; j < 4; j++)
            bhf[j] = *(const bf16x8*)&Bh0[(size_t)j * 16 * Kpad + k0];
        // ---- A fp32 load + in-register split ----
        float fv[16];
        if (k0 + shf * 16 < Kd) {
            *(float4*)&fv[0]  = *(const float4*)&Ab[k0];
            *(float4*)&fv[4]  = *(const float4*)&Ab[k0 + 4];
            *(float4*)&fv[8]  = *(const float4*)&Ab[k0 + 8];
            *(float4*)&fv[12] = *(const float4*)&Ab[k0 + 12];
        } else {
#pragma unroll
            for (int i = 0; i < 16; i++) fv[i] = 0.f;
        }
        __align__(16) unsigned short hv[16], lv[16];
#pragma unroll
        for (int i = 0; i < 16; i++) {
            hv[i] = f2bf(fv[i]);
            lv[i] = f2bf(fv[i] - bf2f(hv[i]));
        }
        __syncthreads();     // previous tile fully consumed
        *(uint4*)&Aw[0]        = *(uint4*)&hv[0];
        *(uint4*)&Aw[8]        = *(uint4*)&hv[8];
        *(uint4*)&Aw[5120]     = *(uint4*)&lv[0];
        *(uint4*)&Aw[5120 + 8] = *(uint4*)&lv[8];
        __syncthreads();     // staging visible
        // ---- B lo fragments (issued early; consumed by last MFMA group) ----
        bf16x8 blf[4];
#pragma unroll
        for (int j = 0; j < 4; j++)
            blf[j] = *(const bf16x8*)&Bo0[(size_t)j * 16 * Kpad + k0];
        // ---- A fragments from LDS ----
        bf16x8 ah[4], al[4];
#pragma unroll
        for (int i = 0; i < 4; i++) {
            int ar = (wm0 + i * 16 + lm) * 40 + qd * 8;
            ah[i] = *(const bf16x8*)&Al[ar];
            al[i] = *(const bf16x8*)&Al[ar + 5120];
        }
        // ---- MFMA: hi*hi, lo*hi, then hi*lo (blf latency hidden) ----
#pragma unroll
        for (int j = 0; j < 4; j++)
#pragma unroll
            for (int i = 0; i < 4; i++)
                acc[i][j] = __builtin_amdgcn_mfma_f32_16x16x32_bf16(
                    ah[i], bhf[j], acc[i][j], 0, 0, 0);
#pragma unroll
        for (int j = 0; j < 4; j++)
#pragma unroll
            for (int i = 0; i < 4; i++)
                acc[i][j] = __builtin_amdgcn_mfma_f32_16x16x32_bf16(
                    al[i], bhf[j], acc[i][j], 0, 0, 0);
#pragma unroll
        for (int j = 0; j < 4; j++)
#pragma unroll
            for (int i = 0; i < 4; i++)
                acc[i][j] = __builtin_amdgcn_mfma_f32_16x16x32_bf16(
                    ah[i], blf[j], acc[i][j], 0, 0, 0);
    }
    float* out = (blockIdx.y == 0) ? t_rel : h;
#pragma unroll
    for (int i = 0; i < 4; i++)
#pragma unroll
        for (int j = 0; j < 4; j++) {
            int row = m0 + wm0 + i * 16 + qd * 4;
            int col = wn0 + j * 16 + lm;
#pragma unroll
            for (int r = 0; r < 4; r++)
                out[(size_t)(row + r) * 128 + col] = acc[i][j][r];
        }
}

// ---------------- CSR build for layer 1 (original edges, no mask) ----------
__global__ __launch_bounds__(1024) void csr_build0(
    const int* __restrict__ gsrc, const int* __restrict__ gdst,
    int* __restrict__ csr_off, int* __restrict__ csr_deg, int* __restrict__ csr_src) {
    __shared__ int cnt[NPER];
    __shared__ int cur[NPER];
    __shared__ int sscan[512];
    const int g = blockIdx.x;
    const int t = threadIdx.x;
    for (int i = t; i < NPER; i += 1024) cnt[i] = 0;
    __syncthreads();
    for (int e = t; e < EPG; e += 1024) {
        int dl = gdst[g * EPG + e] - g * NPER;
        atomicAdd(&cnt[dl], 1);
    }
    __syncthreads();
    if (t < 512) sscan[t] = (t < NPER) ? cnt[t] : 0;
    __syncthreads();
    for (int d = 1; d < 512; d <<= 1) {
        int v = 0;
        if (t < 512 && t >= d) v = sscan[t - d];
        __syncthreads();
        if (t < 512 && t >= d) sscan[t] += v;
        __syncthreads();
    }
    if (t < NPER) {
        int excl = (t == 0) ? 0 : sscan[t - 1];
        int st = g * EPG + excl;
        csr_off[g * NPER + t] = st;
        csr_deg[g * NPER + t] = cnt[t];
        cur[t] = st;
    }
    __syncthreads();
    for (int e = t; e < EPG; e += 1024) {
        int eg = g * EPG + e;
        int dl = gdst[eg] - g * NPER;
        int slot = atomicAdd(&cur[dl], 1);
        csr_src[slot] = gsrc[eg];
    }
}

// ---------------- fused edge remap + CSR build (layers 2,3 conv prep) -------
__global__ __launch_bounds__(1024) void csr_remap(
    const int* __restrict__ es_in, const int* __restrict__ ed_in,
    const int* __restrict__ em_in,
    const int* __restrict__ gsrc, const int* __restrict__ gdst,
    const int* __restrict__ newid,
    int* __restrict__ es_out, int* __restrict__ ed_out, int* __restrict__ em_out,
    int* __restrict__ csr_off, int* __restrict__ csr_deg, int* __restrict__ csr_src,
    int npg_prev, int k, int first) {
    __shared__ int nid[NPER];
    __shared__ int packed[EPG];
    __shared__ int cnt[K1];
    __shared__ int cur[K1];
    __shared__ int sscan[512];
    const int g = blockIdx.x;
    const int t = threadIdx.x;
    for (int i = t; i < npg_prev; i += 1024) nid[i] = newid[g * npg_prev + i];
    for (int i = t; i < k; i += 1024) cnt[i] = 0;
    __syncthreads();
    for (int e = t; e < EPG; e += 1024) {
        int eg = g * EPG + e;
        int sl, dl, m;
        if (first) { sl = gsrc[eg] - g * NPER; dl = gdst[eg] - g * NPER; m = 1; }
        else       { sl = es_in[eg]; dl = ed_in[eg]; m = em_in[eg]; }
        int ns = nid[sl], nd = nid[dl];
        int keep = (m && ns >= 0 && nd >= 0) ? 1 : 0;
        es_out[eg] = keep ? ns : 0;
        ed_out[eg] = keep ? nd : 0;
        em_out[eg] = keep;
        packed[e] = keep ? (ns | (nd << 16)) : -1;
        if (keep) atomicAdd(&cnt[nd], 1);
    }
    __syncthreads();
    if (t < 512) sscan[t] = (t < k) ? cnt[t] : 0;
    __syncthreads();
    for (int d = 1; d < 512; d <<= 1) {
        int v = 0;
        if (t < 512 && t >= d) v = sscan[t - d];
        __syncthreads();
        if (t < 512 && t >= d) sscan[t] += v;
        __syncthreads();
    }
    if (t < k) {
        int excl = (t == 0) ? 0 : sscan[t - 1];
        int st = g * EPG + excl;
        csr_off[g * k + t] = st;
        csr_deg[g * k + t] = cnt[t];
        cur[t] = st;
    }
    __syncthreads();
    for (int e = t; e < EPG; e += 1024) {
        int p = packed[e];
        if (p >= 0) {
            int ns = p & 0xffff, nd = p >> 16;
            int slot = atomicAdd(&cur[nd], 1);
            csr_src[slot] = g * k + ns;
        }
    }
}

// ---------------- Aggregation (gather) + combine + relu + score ------------
__global__ __launch_bounds__(256) void agg_score(
    const float* __restrict__ t_rel,
    const int* __restrict__ csr_off, const int* __restrict__ csr_deg,
    const int* __restrict__ csr_src,
    const float* __restrict__ bias, const float* __restrict__ pw,
    float* __restrict__ h, float* __restrict__ sc, int npg) {
    const int xcd = blockIdx.x & 7;
    const int j = blockIdx.x >> 3;
    const int bpg = npg >> 2;
    const int graph = xcd * (BATCH / 8) + j / bpg;
    const int nblk = j - (j / bpg) * bpg;
    const int wid = graph * npg + nblk * 4 + (threadIdx.x >> 6);
    const int lane = threadIdx.x & 63;

    const int start = csr_off[wid];
    const int deg = csr_deg[wid];
    const size_t fo = (size_t)lane * 2;
    float a0 = 0.f, a1 = 0.f, b0 = 0.f, b1 = 0.f;
    float c0 = 0.f, c1 = 0.f, d0 = 0.f, d1 = 0.f;
    int e = 0;
    for (; e + 4 <= deg; e += 4) {
        int s0 = csr_src[start + e];
        int s1 = csr_src[start + e + 1];
        int s2 = csr_src[start + e + 2];
        int s3 = csr_src[start + e + 3];
        float2 v0 = *(const float2*)&t_rel[(size_t)s0 * 128 + fo];
        float2 v1 = *(const float2*)&t_rel[(size_t)s1 * 128 + fo];
        float2 v2 = *(const float2*)&t_rel[(size_t)s2 * 128 + fo];
        float2 v3 = *(const float2*)&t_rel[(size_t)s3 * 128 + fo];
        a0 += v0.x; a1 += v0.y;
        b0 += v1.x; b1 += v1.y;
        c0 += v2.x; c1 += v2.y;
        d0 += v3.x; d1 += v3.y;
    }
    for (; e < deg; e++) {
        int s0 = csr_src[start + e];
        float2 v0 = *(const float2*)&t_rel[(size_t)s0 * 128 + fo];
        a0 += v0.x; a1 += v0.y;
    }
    a0 += b0 + c0 + d0;
    a1 += b1 + c1 + d1;

    float2 bb = *(const float2*)&bias[fo];
    size_t o = (size_t)wid * 128 + fo;
    float2 hv = *(const float2*)&h[o];
    hv.x = fmaxf(hv.x + a0 + bb.x, 0.f);
    hv.y = fmaxf(hv.y + a1 + bb.y, 0.f);
    *(float2*)&h[o] = hv;
    float2 pp = *(const float2*)&pw[fo];
    float d = hv.x * pp.x + hv.y * pp.y;
    float nr = pp.x * pp.x + pp.y * pp.y;
#pragma unroll
    for (int off = 32; off; off >>= 1) {
        d += __shfl_down(d, off, 64);
        nr += __shfl_down(nr, off, 64);
    }
    if (lane == 0) sc[wid] = d / (sqrtf(nr) + 1e-16f);
}

// ---------------- topk per graph: exact bitonic sort of 512 ----------------
__device__ __forceinline__ bool rank_before(float as, int ai, float bs, int bi) {
    return (as > bs) || (as == bs && ai < bi);
}
__global__ __launch_bounds__(256) void topk_kernel(const float* __restrict__ sc,
                                                   int* __restrict__ idxo,
                                                   float* __restrict__ valso,
                                                   int* __restrict__ newid,
                                                   int npg, int k) {
    __shared__ float sk[512];
    __shared__ int si[512];
    const int g = blockIdx.x;
    for (int t = threadIdx.x; t < 512; t += 256) {
        sk[t] = (t < npg) ? sc[g * npg + t] : -INFINITY;
        si[t] = t;
    }
    __syncthreads();
    for (int size = 2; size <= 512; size <<= 1) {
        for (int stride = size >> 1; stride; stride >>= 1) {
            for (int i = threadIdx.x; i < 512; i += 256) {
                int j = i ^ stride;
                if (j > i) {
                    bool up = ((i & size) == 0);
                    float a = sk[i], b = sk[j];
                    int ai = si[i], bi = si[j];
                    bool doswap = up ? rank_before(b, bi, a, ai)
                                     : rank_before(a, ai, b, bi);
                    if (doswap) { sk[i] = b; sk[j] = a; si[i] = bi; si[j] = ai; }
                }
            }
            __syncthreads();
        }
    }
    for (int t = threadIdx.x; t < 512; t += 256) {
        if (t < npg) {
            int orig = si[t];
            newid[g * npg + orig] = (t < k) ? t : -1;
            if (t < k) { idxo[g * k + t] = orig; valso[g * k + t] = sk[t]; }
        }
    }
}

// ---------------- fused gather+gate+(hp write)+readout ----------------
__global__ __launch_bounds__(512) void pool_readout(
    const float* __restrict__ h, const int* __restrict__ idx,
    const float* __restrict__ vals, float* __restrict__ hp,
    float* __restrict__ z, int npg, int k) {
    __shared__ float tg[K1];
    __shared__ int ix[K1];
    __shared__ float pmx[4][128], psm[4][128];
    const int g = blockIdx.x;
    const int f = threadIdx.x & 127;
    const int jq = threadIdx.x >> 7;
    for (int j = threadIdx.x; j < k; j += 512) {
        tg[j] = tanhf(vals[g * k + j]);
        ix[j] = idx[g * k + j];
    }
    __syncthreads();
    float mx = -INFINITY, sm = 0.f;
    for (int j = jq; j < k; j += 4) {
        float v = h[(size_t)(g * npg + ix[j]) * 128 + f] * tg[j];
        if (hp) hp[(size_t)(g * k + j) * 128 + f] = v;
        mx = fmaxf(mx, v);
        sm += v;
    }
    pmx[jq][f] = mx; psm[jq][f] = sm;
    __syncthreads();
    if (threadIdx.x < 128) {
        mx = fmaxf(fmaxf(pmx[0][f], pmx[1][f]), fmaxf(pmx[2][f], pmx[3][f]));
        sm = psm[0][f] + psm[1][f] + psm[2][f] + psm[3][f];
        z[g * 256 + f] += mx;
        z[g * 256 + 128 + f] += sm / (float)k;
    }
}

// ---------------- MLP head + log_softmax ----------------
__global__ __launch_bounds__(256) void mlp_head(const float* __restrict__ z,
                                                const float* __restrict__ W1,
                                                const float* __restrict__ bl1,
                                                const float* __restrict__ W2,
                                                const float* __restrict__ bl2,
                                                const float* __restrict__ W3,
                                                const float* __restrict__ bl3,
                                                float* __restrict__ out) {
    __shared__ float zs[256], l1[128], l2[64];
    const int g = blockIdx.x, t = threadIdx.x;
    zs[t] = z[g * 256 + t];
    __syncthreads();
    if (t < 128) {
        float s = bl1[t];
        const float* w = &W1[t * 256];
        for (int i = 0; i < 256; i++) s += w[i] * zs[i];
        l1[t] = fmaxf(s, 0.f);
    }
    __syncthreads();
    if (t < 64) {
        float s = bl2[t];
        const float* w = &W2[t * 128];
        for (int i = 0; i < 128; i++) s += w[i] * l1[i];
        l2[t] = fmaxf(s, 0.f);
    }
    __syncthreads();
    if (t == 0) {
        float a = bl3[0], b = bl3[1];
        for (int i = 0; i < 64; i++) { a += W3[i] * l2[i]; b += W3[64 + i] * l2[i]; }
        float m = fmaxf(a, b);
        float lse = m + logf(expf(a - m) + expf(b - m));
        out[g * 2 + 0] = a - lse;
        out[g * 2 + 1] = b - lse;
    }
}

// ---------------- launch ----------------
extern "C" void kernel_launch(void* const* d_in, const int* in_sizes, int n_in,
                              void* d_out, int out_size, void* d_ws, size_t ws_size,
                              hipStream_t stream) {
    const float* x        = (const float*)d_in[0];
    const int*   edge_src = (const int*)d_in[1];
    const int*   edge_dst = (const int*)d_in[2];
    const float* Wrel1 = (const float*)d_in[4];
    const float* Wroot1= (const float*)d_in[5];
    const float* b1    = (const float*)d_in[6];
    const float* pw1   = (const float*)d_in[7];
    const float* Wrel2 = (const float*)d_in[8];
    const float* Wroot2= (const float*)d_in[9];
    const float* b2    = (const float*)d_in[10];
    const float* pw2   = (const float*)d_in[11];
    const float* Wrel3 = (const float*)d_in[12];
    const float* Wroot3= (const float*)d_in[13];
    const float* b3    = (const float*)d_in[14];
    const float* pw3   = (const float*)d_in[15];
    const float* W1    = (const float*)d_in[16];
    const float* bl1   = (const float*)d_in[17];
    const float* W2    = (const float*)d_in[18];
    const float* bl2   = (const float*)d_in[19];
    const float* W3    = (const float*)d_in[20];
    const float* bl3   = (const float*)d_in[21];

    char* ws = (char*)d_ws;
    float* t_rel = (float*)(ws + OFF_TREL);
    float* h     = (float*)(ws + OFF_H);
    float* hp    = (float*)(ws + OFF_HP);
    float* sc    = (float*)(ws + OFF_SC);
    int*   idx   = (int*)(ws + OFF_IDX);
    float* vals  = (float*)(ws + OFF_VALS);
    int*   newid = (int*)(ws + OFF_NEWID);
    int*   es    = (int*)(ws + OFF_ES);
    int*   ed    = (int*)(ws + OFF_ED);
    int*   em    = (int*)(ws + OFF_EM);
    float* z     = (float*)(ws + OFF_Z);
    int*   coff  = (int*)(ws + OFF_COFF);
    int*   cdeg  = (int*)(ws + OFF_CDEG);
    int*   csrc  = (int*)(ws + OFF_CSRC);
    unsigned short* w1h = (unsigned short*)(ws + OFF_W1H);
    unsigned short* w1l = (unsigned short*)(ws + OFF_W1L);
    unsigned short* w2h = (unsigned short*)(ws + OFF_W2H);
    unsigned short* w2l = (unsigned short*)(ws + OFF_W2L);
    unsigned short* w3h = (unsigned short*)(ws + OFF_W3H);
    unsigned short* w3l = (unsigned short*)(ws + OFF_W3L);

    hipMemsetAsync(z, 0, 128ull * 256 * 4, stream);
    prep_w<<<dim3(2, 256), 256, 0, stream>>>(Wrel1, Wroot1, w1h, w1l, F_IN, 416);
    prep_w<<<dim3(1, 256), 256, 0, stream>>>(Wrel2, Wroot2, w2h, w2l, HD, 128);
    prep_w<<<dim3(1, 256), 256, 0, stream>>>(Wrel3, Wroot3, w3h, w3l, HD, 128);
    csr_build0<<<BATCH, 1024, 0, stream>>>(edge_src, edge_dst, coff, cdeg, csrc);

    // ---------- layer 1 ----------
    gemm_mfma<<<dim3(400, 2), 256, 0, stream>>>(x, w1h, w1l, t_rel, h, F_IN, 416, 13);
    agg_score<<<51200 / 4, 256, 0, stream>>>(t_rel, coff, cdeg, csrc, b1, pw1,
                                             h, sc, NPER);
    topk_kernel<<<BATCH, 256, 0, stream>>>(sc, idx, vals, newid, NPER, K1);
    csr_remap<<<BATCH, 1024, 0, stream>>>(nullptr, nullptr, nullptr,
                                          edge_src, edge_dst, newid,
                                          es, ed, em, coff, cdeg, csrc,
                                          NPER, K1, 1);
    pool_readout<<<BATCH, 512, 0, stream>>>(h, idx, vals, hp, z, NPER, K1);

    // ---------- layer 2 ----------
    gemm_mfma<<<dim3(320, 2), 256, 0, stream>>>(hp, w2h, w2l, t_rel, h, HD, 128, 4);
    agg_score<<<40960 / 4, 256, 0, stream>>>(t_rel, coff, cdeg, csrc, b2, pw2,
                                             h, sc, K1);
    topk_kernel<<<BATCH, 256, 0, stream>>>(sc, idx, vals, newid, K1, K2);
    csr_remap<<<BATCH, 1024, 0, stream>>>(es, ed, em, nullptr, nullptr, newid,
                                          es, ed, em, coff, cdeg, csrc,
                                          K1, K2, 0);
    pool_readout<<<BATCH, 512, 0, stream>>>(h, idx, vals, hp, z, K1, K2);

    // ---------- layer 3 ----------
    gemm_mfma<<<dim3(256, 2), 256, 0, stream>>>(hp, w3h, w3l, t_rel, h, HD, 128, 4);
    agg_score<<<32768 / 4, 256, 0, stream>>>(t_rel, coff, cdeg, csrc, b3, pw3,
                                             h, sc, K2);
    topk_kernel<<<BATCH, 256, 0, stream>>>(sc, idx, vals, newid, K2, K3);
    pool_readout<<<BATCH, 512, 0, stream>>>(h, idx, vals, nullptr, z, K2, K3);

    // ---------- MLP head ----------
    mlp_head<<<BATCH, 256, 0, stream>>>(z, W1, bl1, W2, bl2, W3, bl3, (float*)d_out);
}